// Round 13
// baseline (104.473 us; speedup 1.0000x reference)
//
#include <hip/hip_runtime.h>
#include <hip/hip_bf16.h>
#include <cstddef>

// Problem constants
#define DIMC   128
#define NHEADS 8
#define HDIM   16
#define DD     5
#define HH     24
#define WW_    48
#define NPOS   (DD * HH * WW_)     // 5760
#define SCALE  0.25f

typedef short  bf16x8 __attribute__((ext_vector_type(8)));
typedef float  f32x4  __attribute__((ext_vector_type(4)));

__device__ __forceinline__ unsigned short f2bf(float f) {
    unsigned u = __float_as_uint(f);
    u = (u + 0x7FFFu + ((u >> 16) & 1u)) >> 16;   // RNE
    return (unsigned short)u;
}
__device__ __forceinline__ float bf2f(unsigned short s) {
    return __uint_as_float(((unsigned)s) << 16);
}

// ---------------------------------------------------------------------------
// QKV GEMM with fused fp32->bf16 hi/lo conversion (R10-verbatim) + zero-fill
// of `out` (the attn+proj kernel accumulates into out with atomics, so out
// must be zeroed each call; d_out is re-poisoned 0xAA before every launch).
// ---------------------------------------------------------------------------
__global__ __launch_bounds__(256, 3) void gemm_qkv_kernel(
    const float* __restrict__ x,
    const float* __restrict__ wq,
    const float* __restrict__ qkv_b,
    unsigned short* __restrict__ Qhl,
    unsigned short* __restrict__ Kbf,
    unsigned short* __restrict__ Vbf,
    float* __restrict__ out)
{
    __shared__ __align__(16) unsigned short Bs[64][264];  // [hi128|lo128|pad8]

    const int tid = threadIdx.x;
    const int bn  = blockIdx.x * 64;
    const int bm  = blockIdx.y * 64;
    const int bid = blockIdx.y * 6 + blockIdx.x;   // 0..539

    // zero-fill out: 184320 float4 over 540 blocks (issue early, independent)
    {
        float4* o4 = (float4*)out;
        const float4 z = make_float4(0.f, 0.f, 0.f, 0.f);
        for (int i = bid * 256 + tid; i < 184320; i += 540 * 256) o4[i] = z;
    }

    for (int i = tid; i < 2048; i += 256) {
        const int r = i >> 5, c4 = (i & 31) * 4;
        const float4 v = *(const float4*)(wq + (size_t)(bn + r) * 128 + c4);
        ushort4 hi, lo;
        hi.x = f2bf(v.x); hi.y = f2bf(v.y); hi.z = f2bf(v.z); hi.w = f2bf(v.w);
        lo.x = f2bf(v.x - bf2f(hi.x));
        lo.y = f2bf(v.y - bf2f(hi.y));
        lo.z = f2bf(v.z - bf2f(hi.z));
        lo.w = f2bf(v.w - bf2f(hi.w));
        *(ushort4*)(&Bs[r][c4])       = hi;
        *(ushort4*)(&Bs[r][128 + c4]) = lo;
    }
    __syncthreads();

    const int w    = tid >> 6;
    const int lane = tid & 63;
    const int ln   = lane & 15;
    const int quad = lane >> 4;
    const int row  = bm + w * 16 + ln;
    const float* ar = x + (size_t)row * 128 + quad * 8;

    f32x4 acc[4] = {};
    #pragma unroll
    for (int kcg = 0; kcg < 4; ++kcg) {
        const float4 xa = *(const float4*)(ar + kcg * 32);
        const float4 xb = *(const float4*)(ar + kcg * 32 + 4);
        bf16x8 ahi, alo;
        {
            const float vv[8] = {xa.x, xa.y, xa.z, xa.w, xb.x, xb.y, xb.z, xb.w};
            #pragma unroll
            for (int j = 0; j < 8; ++j) {
                const unsigned short hh = f2bf(vv[j]);
                ahi[j] = (short)hh;
                alo[j] = (short)f2bf(vv[j] - bf2f(hh));
            }
        }
        #pragma unroll
        for (int nt = 0; nt < 4; ++nt) {
            const bf16x8 bhi = *(const bf16x8*)(&Bs[nt * 16 + ln][kcg * 32 + quad * 8]);
            const bf16x8 blo = *(const bf16x8*)(&Bs[nt * 16 + ln][128 + kcg * 32 + quad * 8]);
            acc[nt] = __builtin_amdgcn_mfma_f32_16x16x32_bf16(ahi, bhi, acc[nt], 0, 0, 0);
            acc[nt] = __builtin_amdgcn_mfma_f32_16x16x32_bf16(alo, bhi, acc[nt], 0, 0, 0);
            acc[nt] = __builtin_amdgcn_mfma_f32_16x16x32_bf16(ahi, blo, acc[nt], 0, 0, 0);
        }
    }

    #pragma unroll
    for (int nt = 0; nt < 4; ++nt) {
        const int col = bn + nt * 16 + ln;
        const float bv = qkv_b[col];
        #pragma unroll
        for (int r = 0; r < 4; ++r) {
            const int orow = bm + w * 16 + quad * 4 + r;
            const float val = acc[nt][r] + bv;
            if (col < 128) {               // q -> hi/lo pair
                const int h = col >> 4, ci = col & 15;
                const unsigned short hi = f2bf(val);
                Qhl[(size_t)orow * 256 + h * 32 + ci]      = hi;
                Qhl[(size_t)orow * 256 + h * 32 + 16 + ci] = f2bf(val - bf2f(hi));
            } else if (col < 256) {        // k -> bf16
                Kbf[(size_t)orow * 128 + (col - 128)] = f2bf(val);
            } else {                       // v -> bf16
                Vbf[(size_t)orow * 128 + (col - 256)] = f2bf(val);
            }
        }
    }
}

// ---------------------------------------------------------------------------
// Fused attention + projection. Attn body = R10 verbatim. New epilogue:
// normalized A_h (80x16) -> LDS as [hi16|lo16], W_h (proj_w cols h*16..+16)
// -> LDS as [Whi16|Wlo16], then a 40-tile mini-GEMM:
//   out[m][n] += Sum_k A_h[m][k] * W_h[n][k]
// via 2 MFMAs/tile: [hi|hi]x[Whi|Wlo] + [lo|0]x[Whi|Wlo] (3-term split).
// Partials accumulated across the 8 head-blocks with global fp32 atomics
// (disjoint-address, hardware global_atomic_add_f32); h==0 adds bias.
// LDS 35072 B -> still 4 blocks/CU.
// ---------------------------------------------------------------------------
__global__ __launch_bounds__(256, 3) void attn_proj_kernel(
    const unsigned short* __restrict__ Qhl,   // [5760][256] bf16 per-head hi|lo
    const unsigned short* __restrict__ Kbf,   // [5760][128] bf16
    const unsigned short* __restrict__ Vbf,   // [5760][128] bf16
    const float* __restrict__ wp,             // [128][128] fp32 proj_w
    const float* __restrict__ proj_b,         // [128]
    float* __restrict__ out)                  // [5760][128] fp32 (pre-zeroed)
{
    // LDS: phase1: Vt@0(16640) Qb@16640(6400) Pw@23040(10240) red_l@33792(1280)
    //      phase2 overlay: redO@0(20480) Wb@20480(8192) Ahl@28672(5120)
    __shared__ __align__(16) char smem[35072];
    unsigned short (*Vt)[520] = (unsigned short(*)[520])smem;
    unsigned short (*Qb)[40]  = (unsigned short(*)[40])(smem + 16640);
    unsigned short* PwBase    = (unsigned short*)(smem + 23040);
    float* red_l              = (float*)(smem + 33792);
    float* redO               = (float*)smem;
    unsigned short* Wb        = (unsigned short*)(smem + 20480);  // [128][32]
    unsigned short* Ahl       = (unsigned short*)(smem + 28672);  // [80][32]

    const int tile = blockIdx.x;
    const int h    = blockIdx.y;
    const int ty0  = (tile / 12) * 4;
    const int tx0  = (tile % 12) * 4;
    const int tid  = threadIdx.x;

    // ---- stage V^T (bf16) ----
    for (int i = tid; i < 1024; i += 256) {
        const int u = i >> 1, half = i & 1;
        if (u < 500) {
            const int dp = u / 100;
            const int rr = u - dp * 100;
            const int yy = rr / 10;
            const int xx = rr - yy * 10;
            int y = ty0 - 3 + yy; if (y < 0) y += HH;  if (y >= HH) y -= HH;
            int x = tx0 - 3 + xx; if (x < 0) x += WW_; if (x >= WW_) x -= WW_;
            const int g = (dp * HH + y) * WW_ + x;
            const bf16x8 v = *(const bf16x8*)(Vbf + (size_t)g * 128 + h * 16 + half * 8);
            #pragma unroll
            for (int c = 0; c < 8; ++c) Vt[half * 8 + c][u] = (unsigned short)v[c];
        } else {
            #pragma unroll
            for (int c = 0; c < 8; ++c) Vt[half * 8 + c][u] = 0;
        }
    }
    // ---- stage Q tile (straight bf16 copy) ----
    for (int i = tid; i < 320; i += 256) {
        const int p = i >> 2, seg = i & 3;
        const int d = p >> 4, s = p & 15;
        const int sy = s >> 2, sx = s & 3;
        const int g = (d * HH + ty0 + sy) * WW_ + tx0 + sx;
        *(bf16x8*)(&Qb[p][seg * 8]) = *(const bf16x8*)(Qhl + (size_t)g * 256 + h * 32 + seg * 8);
    }
    __syncthreads();

    const int w    = tid >> 6;
    const int lane = tid & 63;
    const int ln   = lane & 15;
    const int quad = lane >> 4;
    const int sy   = ln >> 2, sx = ln & 3;

    unsigned short* Pw = PwBase + w * 1280;  // [2][16][40]

    bf16x8 qf[5];
    #pragma unroll
    for (int mt = 0; mt < 5; ++mt)
        qf[mt] = *(const bf16x8*)(&Qb[mt * 16 + ln][quad * 8]);

    f32x4 Ow[5] = {};
    float lsum[5] = {};

    for (int chunk = 0; chunk < 4; ++chunk) {
        const int u0 = (w * 4 + chunk) * 32;

        int rowa, rowb;
        {
            const int ua = u0 + ln      < 500 ? u0 + ln      : 499;
            const int ub = u0 + 16 + ln < 500 ? u0 + 16 + ln : 499;
            int dp = ua / 100, rr = ua - dp * 100, yy = rr / 10, xx = rr - yy * 10;
            int y = ty0 - 3 + yy; if (y < 0) y += HH;  if (y >= HH) y -= HH;
            int x = tx0 - 3 + xx; if (x < 0) x += WW_; if (x >= WW_) x -= WW_;
            rowa = (dp * HH + y) * WW_ + x;
            dp = ub / 100; rr = ub - dp * 100; yy = rr / 10; xx = rr - yy * 10;
            y = ty0 - 3 + yy; if (y < 0) y += HH;  if (y >= HH) y -= HH;
            x = tx0 - 3 + xx; if (x < 0) x += WW_; if (x >= WW_) x -= WW_;
            rowb = (dp * HH + y) * WW_ + x;
        }
        const bf16x8 ka = *(const bf16x8*)(Kbf + (size_t)rowa * 128 + h * 16 + (quad & 1) * 8);
        const bf16x8 kb = *(const bf16x8*)(Kbf + (size_t)rowb * 128 + h * 16 + (quad & 1) * 8);

        bool msk[2][4];
        #pragma unroll
        for (int b = 0; b < 2; ++b)
            #pragma unroll
            for (int r = 0; r < 4; ++r) {
                const int u = u0 + 16 * b + 4 * quad + r;
                const int rr = u % 100;
                const int uy = rr / 10, ux = rr - uy * 10;
                msk[b][r] = (u < 500) && ((unsigned)(uy - sy) <= 6u)
                                      && ((unsigned)(ux - sx) <= 6u);
            }

        const bf16x8 vf = *(const bf16x8*)(&Vt[ln][u0 + quad * 8]);

        #pragma unroll
        for (int mt = 0; mt < 5; ++mt) {
            f32x4 s0 = __builtin_amdgcn_mfma_f32_16x16x32_bf16(
                ka, qf[mt], (f32x4){0.f, 0.f, 0.f, 0.f}, 0, 0, 0);
            f32x4 s1 = __builtin_amdgcn_mfma_f32_16x16x32_bf16(
                kb, qf[mt], (f32x4){0.f, 0.f, 0.f, 0.f}, 0, 0, 0);

            unsigned short* pw = Pw + (mt & 1) * 640 + ln * 40;
            #pragma unroll
            for (int b = 0; b < 2; ++b) {
                const f32x4 s = b ? s1 : s0;
                unsigned short e[4];
                #pragma unroll
                for (int r = 0; r < 4; ++r) {
                    const float ev = msk[b][r] ? __expf(fmaf(s[r], SCALE, -8.0f)) : 0.f;
                    e[r] = f2bf(ev);
                    lsum[mt] += bf2f(e[r]);
                }
                *(unsigned*)(pw + 16 * b + 4 * quad)     = (unsigned)e[0] | ((unsigned)e[1] << 16);
                *(unsigned*)(pw + 16 * b + 4 * quad + 2) = (unsigned)e[2] | ((unsigned)e[3] << 16);
            }
            const bf16x8 pf = *(const bf16x8*)(Pw + (mt & 1) * 640 + ln * 40 + quad * 8);
            Ow[mt] = __builtin_amdgcn_mfma_f32_16x16x32_bf16(vf, pf, Ow[mt], 0, 0, 0);
        }
    }

    // l: reduce across quads (lanes ln+16q hold disjoint u-partials)
    #pragma unroll
    for (int mt = 0; mt < 5; ++mt) {
        lsum[mt] += __shfl_xor(lsum[mt], 16);
        lsum[mt] += __shfl_xor(lsum[mt], 32);
    }

    __syncthreads();   // all Vt/Qb/Pw reads done; safe to overlay redO/Wb

    if (quad == 0) {
        #pragma unroll
        for (int mt = 0; mt < 5; ++mt)
            red_l[w * 80 + mt * 16 + ln] = lsum[mt];
    }
    #pragma unroll
    for (int mt = 0; mt < 5; ++mt)
        #pragma unroll
        for (int r = 0; r < 4; ++r)
            redO[(size_t)((w * 5 + mt) * 16 + quad * 4 + r) * 16 + ln] = Ow[mt][r];
    // stage W_h: Wb[n][0..15]=hi(proj_w[n][h*16+k]), [16..31]=lo
    for (int i = tid; i < 2048; i += 256) {
        const int n = i >> 4, kk = i & 15;
        const float v = wp[(size_t)n * 128 + h * 16 + kk];
        const unsigned short hi = f2bf(v);
        Wb[n * 32 + kk]      = hi;
        Wb[n * 32 + 16 + kk] = f2bf(v - bf2f(hi));
    }
    __syncthreads();

    // epilogue: normalize, write A_h into LDS as [hi16|lo16]
    for (int i = tid; i < 1280; i += 256) {
        const int m = i >> 4, c = i & 15;
        const int mt = m >> 4, mloc = m & 15;
        float o = 0.f, l = 0.f;
        #pragma unroll
        for (int w4 = 0; w4 < 4; ++w4) {
            o += redO[(size_t)((w4 * 5 + mt) * 16 + c) * 16 + mloc];
            l += red_l[w4 * 80 + m];
        }
        const float val = o / l;
        const unsigned short hi = f2bf(val);
        Ahl[m * 32 + c]      = hi;
        Ahl[m * 32 + 16 + c] = f2bf(val - bf2f(hi));
    }
    __syncthreads();

    // mini proj GEMM: 40 tiles (5 mt x 8 nt), wave w takes t % 4 == w.
    // out[m][n] += A_h[m] . W_h[n]; C/D: row m = mt*16+quad*4+r, col n = nt*16+ln
    for (int t = w; t < 40; t += 4) {
        const int mt = t >> 3, nt = t & 7;
        const unsigned short* am = Ahl + (mt * 16 + ln) * 32;
        const bf16x8 a1 = *(const bf16x8*)(am + (quad & 1) * 8);          // [hi|hi]
        bf16x8 a2 = {0, 0, 0, 0, 0, 0, 0, 0};                             // [lo|0]
        if (quad < 2) a2 = *(const bf16x8*)(am + 16 + quad * 8);
        const bf16x8 b = *(const bf16x8*)(Wb + (nt * 16 + ln) * 32 + quad * 8); // [Whi|Wlo]
        f32x4 acc = __builtin_amdgcn_mfma_f32_16x16x32_bf16(a1, b, (f32x4){0.f,0.f,0.f,0.f}, 0, 0, 0);
        acc = __builtin_amdgcn_mfma_f32_16x16x32_bf16(a2, b, acc, 0, 0, 0);
        const int col = nt * 16 + ln;
        const float bias = (h == 0) ? proj_b[col] : 0.f;
        #pragma unroll
        for (int r = 0; r < 4; ++r) {
            // m = mt*16 + quad*4 + r -> depth mt, y = ty0+quad, x = tx0+r
            const size_t g = (size_t)((mt * HH + ty0 + quad) * WW_ + (tx0 + r));
            atomicAdd(&out[g * 128 + col], acc[r] + bias);
        }
    }
}

// ---------------------------------------------------------------------------
extern "C" void kernel_launch(void* const* d_in, const int* in_sizes, int n_in,
                              void* d_out, int out_size, void* d_ws, size_t ws_size,
                              hipStream_t stream)
{
    const float* x      = (const float*)d_in[0];
    const float* qkv_w  = (const float*)d_in[1];
    const float* qkv_b  = (const float*)d_in[2];
    const float* proj_w = (const float*)d_in[3];
    const float* proj_b = (const float*)d_in[4];
    float* out = (float*)d_out;

    char* ws = (char*)d_ws;
    unsigned short* Qhl = (unsigned short*)ws;  ws += (size_t)NPOS * 256 * 2;
    unsigned short* Kbf = (unsigned short*)ws;  ws += (size_t)NPOS * 128 * 2;
    unsigned short* Vbf = (unsigned short*)ws;  ws += (size_t)NPOS * 128 * 2;

    // 1. QKV GEMM (+ zero-fill of out for the atomic accumulation)
    {
        dim3 grid(384 / 64, NPOS / 64);
        gemm_qkv_kernel<<<grid, 256, 0, stream>>>(x, qkv_w, qkv_b, Qhl, Kbf, Vbf, out);
    }
    // 2. fused attention + projection (atomic accumulate into out)
    {
        dim3 grid(72, NHEADS);
        attn_proj_kernel<<<grid, 256, 0, stream>>>(Qhl, Kbf, Vbf, proj_w, proj_b, out);
    }
}

// Round 14
// 101.081 us; speedup vs baseline: 1.0336x; 1.0336x over previous
//
#include <hip/hip_runtime.h>
#include <hip/hip_bf16.h>
#include <cstddef>

// Problem constants
#define DIMC   128
#define NHEADS 8
#define HDIM   16
#define DD     5
#define HH     24
#define WW_    48
#define NPOS   (DD * HH * WW_)     // 5760
#define SCALE  0.25f

typedef short  bf16x8 __attribute__((ext_vector_type(8)));
typedef float  f32x4  __attribute__((ext_vector_type(4)));

__device__ __forceinline__ unsigned short f2bf(float f) {
    unsigned u = __float_as_uint(f);
    u = (u + 0x7FFFu + ((u >> 16) & 1u)) >> 16;   // RNE
    return (unsigned short)u;
}
__device__ __forceinline__ float bf2f(unsigned short s) {
    return __uint_as_float(((unsigned)s) << 16);
}

// ---------------------------------------------------------------------------
// QKV GEMM with fused fp32->bf16 hi/lo conversion (R11 verbatim).
// ---------------------------------------------------------------------------
__global__ __launch_bounds__(256, 3) void gemm_qkv_kernel(
    const float* __restrict__ x,
    const float* __restrict__ wq,
    const float* __restrict__ qkv_b,
    unsigned short* __restrict__ Qhl,
    unsigned short* __restrict__ Kbf,
    unsigned short* __restrict__ Vbf)
{
    __shared__ __align__(16) unsigned short Bs[64][264];  // [hi128|lo128|pad8]

    const int tid = threadIdx.x;
    const int bn  = blockIdx.x * 64;
    const int bm  = blockIdx.y * 64;

    for (int i = tid; i < 2048; i += 256) {
        const int r = i >> 5, c4 = (i & 31) * 4;
        const float4 v = *(const float4*)(wq + (size_t)(bn + r) * 128 + c4);
        ushort4 hi, lo;
        hi.x = f2bf(v.x); hi.y = f2bf(v.y); hi.z = f2bf(v.z); hi.w = f2bf(v.w);
        lo.x = f2bf(v.x - bf2f(hi.x));
        lo.y = f2bf(v.y - bf2f(hi.y));
        lo.z = f2bf(v.z - bf2f(hi.z));
        lo.w = f2bf(v.w - bf2f(hi.w));
        *(ushort4*)(&Bs[r][c4])       = hi;
        *(ushort4*)(&Bs[r][128 + c4]) = lo;
    }
    __syncthreads();

    const int w    = tid >> 6;
    const int lane = tid & 63;
    const int ln   = lane & 15;
    const int quad = lane >> 4;
    const int row  = bm + w * 16 + ln;
    const float* ar = x + (size_t)row * 128 + quad * 8;

    f32x4 acc[4] = {};
    #pragma unroll
    for (int kcg = 0; kcg < 4; ++kcg) {
        const float4 xa = *(const float4*)(ar + kcg * 32);
        const float4 xb = *(const float4*)(ar + kcg * 32 + 4);
        bf16x8 ahi, alo;
        {
            const float vv[8] = {xa.x, xa.y, xa.z, xa.w, xb.x, xb.y, xb.z, xb.w};
            #pragma unroll
            for (int j = 0; j < 8; ++j) {
                const unsigned short hh = f2bf(vv[j]);
                ahi[j] = (short)hh;
                alo[j] = (short)f2bf(vv[j] - bf2f(hh));
            }
        }
        #pragma unroll
        for (int nt = 0; nt < 4; ++nt) {
            const bf16x8 bhi = *(const bf16x8*)(&Bs[nt * 16 + ln][kcg * 32 + quad * 8]);
            const bf16x8 blo = *(const bf16x8*)(&Bs[nt * 16 + ln][128 + kcg * 32 + quad * 8]);
            acc[nt] = __builtin_amdgcn_mfma_f32_16x16x32_bf16(ahi, bhi, acc[nt], 0, 0, 0);
            acc[nt] = __builtin_amdgcn_mfma_f32_16x16x32_bf16(alo, bhi, acc[nt], 0, 0, 0);
            acc[nt] = __builtin_amdgcn_mfma_f32_16x16x32_bf16(ahi, blo, acc[nt], 0, 0, 0);
        }
    }

    #pragma unroll
    for (int nt = 0; nt < 4; ++nt) {
        const int col = bn + nt * 16 + ln;
        const float bv = qkv_b[col];
        #pragma unroll
        for (int r = 0; r < 4; ++r) {
            const int orow = bm + w * 16 + quad * 4 + r;
            const float val = acc[nt][r] + bv;
            if (col < 128) {
                const int h = col >> 4, ci = col & 15;
                const unsigned short hi = f2bf(val);
                Qhl[(size_t)orow * 256 + h * 32 + ci]      = hi;
                Qhl[(size_t)orow * 256 + h * 32 + 16 + ci] = f2bf(val - bf2f(hi));
            } else if (col < 256) {
                Kbf[(size_t)orow * 128 + (col - 128)] = f2bf(val);
            } else {
                Vbf[(size_t)orow * 128 + (col - 256)] = f2bf(val);
            }
        }
    }
}

// ---------------------------------------------------------------------------
// Proj GEMM (R11 verbatim): out = ((O0+O1) * 1/(l0+l1)) @ proj_w^T + b.
// ---------------------------------------------------------------------------
__global__ __launch_bounds__(128, 2) void gemm_proj_kernel(
    const float* __restrict__ Opart,   // [2][5760][128] fp32 unnormalized
    const float* __restrict__ Lpart,   // [2][5760][8]   fp32 row-sums
    const float* __restrict__ wp,
    const float* __restrict__ proj_b,
    float* __restrict__ out)
{
    __shared__ __align__(16) unsigned short Bs[64][264];

    const int tid = threadIdx.x;
    const int bn  = blockIdx.x * 64;
    const int bm  = blockIdx.y * 32;

    for (int i = tid; i < 2048; i += 128) {
        const int r = i >> 5, c4 = (i & 31) * 4;
        const float4 v = *(const float4*)(wp + (size_t)(bn + r) * 128 + c4);
        ushort4 hi, lo;
        hi.x = f2bf(v.x); hi.y = f2bf(v.y); hi.z = f2bf(v.z); hi.w = f2bf(v.w);
        lo.x = f2bf(v.x - bf2f(hi.x));
        lo.y = f2bf(v.y - bf2f(hi.y));
        lo.z = f2bf(v.z - bf2f(hi.z));
        lo.w = f2bf(v.w - bf2f(hi.w));
        *(ushort4*)(&Bs[r][c4])       = hi;
        *(ushort4*)(&Bs[r][128 + c4]) = lo;
    }
    __syncthreads();

    const int w    = tid >> 6;
    const int lane = tid & 63;
    const int ln   = lane & 15;
    const int quad = lane >> 4;
    const int row  = bm + w * 16 + ln;

    float linv[8];
    {
        const float4 l0a = *(const float4*)(Lpart + (size_t)row * 8);
        const float4 l0b = *(const float4*)(Lpart + (size_t)row * 8 + 4);
        const float4 l1a = *(const float4*)(Lpart + (size_t)(NPOS + row) * 8);
        const float4 l1b = *(const float4*)(Lpart + (size_t)(NPOS + row) * 8 + 4);
        linv[0] = 1.0f / (l0a.x + l1a.x); linv[1] = 1.0f / (l0a.y + l1a.y);
        linv[2] = 1.0f / (l0a.z + l1a.z); linv[3] = 1.0f / (l0a.w + l1a.w);
        linv[4] = 1.0f / (l0b.x + l1b.x); linv[5] = 1.0f / (l0b.y + l1b.y);
        linv[6] = 1.0f / (l0b.z + l1b.z); linv[7] = 1.0f / (l0b.w + l1b.w);
    }
    const float* o0 = Opart + (size_t)row * 128 + quad * 8;
    const float* o1 = o0 + (size_t)NPOS * 128;

    f32x4 acc[4] = {};
    #pragma unroll
    for (int kcg = 0; kcg < 4; ++kcg) {
        const float4 a0 = *(const float4*)(o0 + kcg * 32);
        const float4 a0b = *(const float4*)(o0 + kcg * 32 + 4);
        const float4 a1 = *(const float4*)(o1 + kcg * 32);
        const float4 a1b = *(const float4*)(o1 + kcg * 32 + 4);
        const float inv = linv[kcg * 2 + (quad >> 1)];
        const float vv[8] = {
            (a0.x + a1.x) * inv, (a0.y + a1.y) * inv,
            (a0.z + a1.z) * inv, (a0.w + a1.w) * inv,
            (a0b.x + a1b.x) * inv, (a0b.y + a1b.y) * inv,
            (a0b.z + a1b.z) * inv, (a0b.w + a1b.w) * inv };
        bf16x8 ahi, alo;
        #pragma unroll
        for (int j = 0; j < 8; ++j) {
            const unsigned short hh = f2bf(vv[j]);
            ahi[j] = (short)hh;
            alo[j] = (short)f2bf(vv[j] - bf2f(hh));
        }
        #pragma unroll
        for (int nt = 0; nt < 4; ++nt) {
            const bf16x8 bhi = *(const bf16x8*)(&Bs[nt * 16 + ln][kcg * 32 + quad * 8]);
            const bf16x8 blo = *(const bf16x8*)(&Bs[nt * 16 + ln][128 + kcg * 32 + quad * 8]);
            acc[nt] = __builtin_amdgcn_mfma_f32_16x16x32_bf16(ahi, bhi, acc[nt], 0, 0, 0);
            acc[nt] = __builtin_amdgcn_mfma_f32_16x16x32_bf16(alo, bhi, acc[nt], 0, 0, 0);
            acc[nt] = __builtin_amdgcn_mfma_f32_16x16x32_bf16(ahi, blo, acc[nt], 0, 0, 0);
        }
    }

    #pragma unroll
    for (int nt = 0; nt < 4; ++nt) {
        const int col = bn + nt * 16 + ln;
        const float bv = proj_b[col];
        #pragma unroll
        for (int r = 0; r < 4; ++r) {
            const int orow = bm + w * 16 + quad * 4 + r;
            out[(size_t)orow * 128 + col] = acc[nt][r] + bv;
        }
    }
}

// ---------------------------------------------------------------------------
// Attention v4: u-split blocks + wave-per-slab + SHUFFLE-P (no P LDS).
// Grid (144, 8): tile = bx>>1, half = bx&1 (u in [half*256, half*256+256)).
// Block 320 thr = 5 waves; wave w owns depth slab mt=w over the half's 256 u.
// ONE barrier (post-staging); no redO/red_l LDS; direct float4 Opart stores.
// P conversion C/D->B-fragment done in-register: lane (ln,q) needs
// u in {8q..8q+7} for query ln; producers are quads {2q mod 4, +1}, same ln
// -> 8 __shfl + 4 selects replace the LDS write/lgkmcnt/read roundtrip.
// Vt row stride 258 (de-conflicts staging writes: rows c, c+8 no longer
// alias banks). Mask/row LUTs built once in LDS.
// ---------------------------------------------------------------------------
__global__ __launch_bounds__(320, 4) void attn_kernel(
    const unsigned short* __restrict__ Qhl,   // [5760][256] bf16 per-head hi|lo
    const unsigned short* __restrict__ Kbf,   // [5760][128] bf16
    const unsigned short* __restrict__ Vbf,   // [5760][128] bf16
    float* __restrict__ Opart,                // [2][5760][128] fp32
    float* __restrict__ Lpart)                // [2][5760][8]   fp32
{
    __shared__ __align__(16) unsigned short Vt[16][258];   // 8256 B, V^T
    __shared__ __align__(16) unsigned short Qb[80][40];    // 6400 B, [hi|lo|pad]
    __shared__ int RowL[256];                              // 1024 B
    __shared__ unsigned short Mb[16][18];                  //  576 B mask bits

    const int bx   = blockIdx.x;
    const int tile = bx >> 1;
    const int half = bx & 1;
    const int h    = blockIdx.y;
    const int ty0  = (tile / 12) * 4;
    const int tx0  = (tile % 12) * 4;
    const int tid  = threadIdx.x;

    // ---- RowL: u_local -> wrapped global row (clamped at 499) ----
    for (int ul = tid; ul < 256; ul += 320) {
        int u = half * 256 + ul; if (u > 499) u = 499;
        const int dp = u / 100, rr = u % 100;
        const int uy = rr / 10,  ux = rr % 10;
        int y = ty0 - 3 + uy; if (y < 0) y += HH;  if (y >= HH) y -= HH;
        int x = tx0 - 3 + ux; if (x < 0) x += WW_; if (x >= WW_) x -= WW_;
        RowL[ul] = (dp * HH + y) * WW_ + x;
    }
    // ---- Mb[ln][t]: bit b = (u = half*256 + 16t + b valid for query ln) ----
    for (int i = tid; i < 256; i += 320) {
        const int t = i >> 4, ql = i & 15;
        const int qsy = ql >> 2, qsx = ql & 3;
        unsigned bits = 0;
        #pragma unroll
        for (int b = 0; b < 16; ++b) {
            const int u = half * 256 + t * 16 + b;
            const int rr = u % 100;
            const int uy = rr / 10, ux = rr % 10;
            if (u < 500 && (unsigned)(uy - qsy) <= 6u && (unsigned)(ux - qsx) <= 6u)
                bits |= 1u << b;
        }
        Mb[ql][t] = (unsigned short)bits;
    }
    // ---- stage V^T for this half (512 items) ----
    for (int i = tid; i < 512; i += 320) {
        const int ul = i >> 1, hf8 = i & 1;
        const int u  = half * 256 + ul;
        if (u < 500) {
            const int dp = u / 100, rr = u % 100;
            const int uy = rr / 10,  ux = rr % 10;
            int y = ty0 - 3 + uy; if (y < 0) y += HH;  if (y >= HH) y -= HH;
            int x = tx0 - 3 + ux; if (x < 0) x += WW_; if (x >= WW_) x -= WW_;
            const int g = (dp * HH + y) * WW_ + x;
            const bf16x8 v = *(const bf16x8*)(Vbf + (size_t)g * 128 + h * 16 + hf8 * 8);
            #pragma unroll
            for (int c = 0; c < 8; ++c) Vt[hf8 * 8 + c][ul] = (unsigned short)v[c];
        } else {
            #pragma unroll
            for (int c = 0; c < 8; ++c) Vt[hf8 * 8 + c][ul] = 0;
        }
    }
    // ---- stage Q tile: 320 items == 320 threads ----
    {
        const int p = tid >> 2, seg = tid & 3;
        const int d = p >> 4, s = p & 15;
        const int qsy = s >> 2, qsx = s & 3;
        const int g = (d * HH + ty0 + qsy) * WW_ + tx0 + qsx;
        *(bf16x8*)(&Qb[p][seg * 8]) = *(const bf16x8*)(Qhl + (size_t)g * 256 + h * 32 + seg * 8);
    }
    __syncthreads();   // the only barrier

    const int w    = tid >> 6;    // wave = depth slab mt (0..4)
    const int lane = tid & 63;
    const int ln   = lane & 15;
    const int quad = lane >> 4;

    const bf16x8 qf = *(const bf16x8*)(&Qb[w * 16 + ln][quad * 8]);
    f32x4 Ow = {0.f, 0.f, 0.f, 0.f};
    float lsum = 0.f;

    const int koff = h * 16 + (quad & 1) * 8;
    const int qa   = (quad & 1) << 1;       // source quad A: 0,2,0,2
    const int srcA = ln + (qa << 4);
    const int srcB = srcA + 16;             // source quad B = qa+1
    const bool hi2 = quad >= 2;

    #pragma unroll 2
    for (int c = 0; c < 8; ++c) {
        const int u0l = c * 32;
        const int g0 = RowL[u0l + ln];
        const int g1 = RowL[u0l + 16 + ln];
        const bf16x8 ka = *(const bf16x8*)(Kbf + (size_t)g0 * 128 + koff);
        const bf16x8 kb = *(const bf16x8*)(Kbf + (size_t)g1 * 128 + koff);
        const unsigned mb = *(const unsigned*)(&Mb[ln][2 * c]);   // tiles 2c|2c+1
        const unsigned m0 = (mb >> (quad * 4)) & 0xF;
        const unsigned m1 = (mb >> (16 + quad * 4)) & 0xF;

        f32x4 s0 = __builtin_amdgcn_mfma_f32_16x16x32_bf16(ka, qf, (f32x4){0.f,0.f,0.f,0.f}, 0, 0, 0);
        f32x4 s1 = __builtin_amdgcn_mfma_f32_16x16x32_bf16(kb, qf, (f32x4){0.f,0.f,0.f,0.f}, 0, 0, 0);

        // exp + mask; lane's own u: s0 -> 4*quad+r, s1 -> 16+4*quad+r
        unsigned short e0[4], e1[4];
        #pragma unroll
        for (int r = 0; r < 4; ++r) {
            const float v0 = ((m0 >> r) & 1u) ? __expf(fmaf(s0[r], SCALE, -8.0f)) : 0.f;
            const float v1 = ((m1 >> r) & 1u) ? __expf(fmaf(s1[r], SCALE, -8.0f)) : 0.f;
            e0[r] = f2bf(v0);
            e1[r] = f2bf(v1);
            lsum += bf2f(e0[r]) + bf2f(e1[r]);
        }
        // pack: dA=(u 4q,4q+1) dB=(4q+2,4q+3) dC=(16+4q,16+4q+1) dD=(16+4q+2,+3)
        const int dA = (int)((unsigned)e0[0] | ((unsigned)e0[1] << 16));
        const int dB = (int)((unsigned)e0[2] | ((unsigned)e0[3] << 16));
        const int dC = (int)((unsigned)e1[0] | ((unsigned)e1[1] << 16));
        const int dD = (int)((unsigned)e1[2] | ((unsigned)e1[3] << 16));

        // quad-shuffle: lane (ln,q) gathers u in {8q..8q+7} for query ln
        const int xA = __shfl(dA, srcA, 64);
        const int yC = __shfl(dC, srcA, 64);
        const int xB = __shfl(dB, srcA, 64);
        const int yD = __shfl(dD, srcA, 64);
        const int zA = __shfl(dA, srcB, 64);
        const int wC = __shfl(dC, srcB, 64);
        const int zB = __shfl(dB, srcB, 64);
        const int wD = __shfl(dD, srcB, 64);

        union { int u[4]; bf16x8 v; } pf;
        pf.u[0] = hi2 ? yC : xA;   // u (8q,   8q+1)
        pf.u[1] = hi2 ? yD : xB;   // u (8q+2, 8q+3)
        pf.u[2] = hi2 ? wC : zA;   // u (8q+4, 8q+5)
        pf.u[3] = hi2 ? wD : zB;   // u (8q+6, 8q+7)

        const bf16x8 vf = *(const bf16x8*)(&Vt[ln][u0l + quad * 8]);
        Ow = __builtin_amdgcn_mfma_f32_16x16x32_bf16(vf, pf.v, Ow, 0, 0, 0);
    }

    // l: lanes (ln, quad) hold disjoint u-partials -> reduce across quads
    lsum += __shfl_xor(lsum, 16);
    lsum += __shfl_xor(lsum, 32);

    // direct store: lane holds O^T[ch = quad*4+r][query ln] for slab w
    const int qsy = ln >> 2, qsx = ln & 3;
    const size_t g = (size_t)((w * HH + ty0 + qsy) * WW_ + (tx0 + qsx));
    *(float4*)(Opart + ((size_t)half * NPOS + g) * 128 + h * 16 + quad * 4) =
        make_float4(Ow[0], Ow[1], Ow[2], Ow[3]);
    if (quad == 0)
        Lpart[((size_t)half * NPOS + g) * 8 + h] = lsum;
}

// ---------------------------------------------------------------------------
extern "C" void kernel_launch(void* const* d_in, const int* in_sizes, int n_in,
                              void* d_out, int out_size, void* d_ws, size_t ws_size,
                              hipStream_t stream)
{
    const float* x      = (const float*)d_in[0];
    const float* qkv_w  = (const float*)d_in[1];
    const float* qkv_b  = (const float*)d_in[2];
    const float* proj_w = (const float*)d_in[3];
    const float* proj_b = (const float*)d_in[4];
    float* out = (float*)d_out;

    char* ws = (char*)d_ws;
    unsigned short* Qhl   = (unsigned short*)ws;  ws += (size_t)NPOS * 256 * 2;
    unsigned short* Kbf   = (unsigned short*)ws;  ws += (size_t)NPOS * 128 * 2;
    unsigned short* Vbf   = (unsigned short*)ws;  ws += (size_t)NPOS * 128 * 2;
    float*          Opart = (float*)ws;           ws += (size_t)2 * NPOS * 128 * 4;
    float*          Lpart = (float*)ws;           ws += (size_t)2 * NPOS * 8 * 4;

    // 1. QKV GEMM -> Qhl, Kbf, Vbf
    {
        dim3 grid(384 / 64, NPOS / 64);
        gemm_qkv_kernel<<<grid, 256, 0, stream>>>(x, qkv_w, qkv_b, Qhl, Kbf, Vbf);
    }
    // 2. attention (u-split, wave-per-slab, shuffle-P) -> Opart/Lpart
    {
        dim3 grid(144, NHEADS);
        attn_kernel<<<grid, 320, 0, stream>>>(Qhl, Kbf, Vbf, Opart, Lpart);
    }
    // 3. proj GEMM (combine halves + normalize + GEMM) -> out
    {
        dim3 grid(DIMC / 64, NPOS / 32);
        gemm_proj_kernel<<<grid, 128, 0, stream>>>(Opart, Lpart, proj_w, proj_b, out);
    }
}

// Round 15
// 99.826 us; speedup vs baseline: 1.0465x; 1.0126x over previous
//
#include <hip/hip_runtime.h>
#include <hip/hip_bf16.h>
#include <cstddef>

// Problem constants
#define DIMC   128
#define NHEADS 8
#define HDIM   16
#define DD     5
#define HH     24
#define WW_    48
#define NPOS   (DD * HH * WW_)     // 5760
#define SCALE  0.25f

typedef short  bf16x8 __attribute__((ext_vector_type(8)));
typedef float  f32x4  __attribute__((ext_vector_type(4)));

__device__ __forceinline__ unsigned short f2bf(float f) {
    unsigned u = __float_as_uint(f);
    u = (u + 0x7FFFu + ((u >> 16) & 1u)) >> 16;   // RNE
    return (unsigned short)u;
}
__device__ __forceinline__ float bf2f(unsigned short s) {
    return __uint_as_float(((unsigned)s) << 16);
}

// ---------------------------------------------------------------------------
// QKV GEMM with fused fp32->bf16 hi/lo conversion (R11 structure).
// Epilogue change: K/V written CO-LOCATED head-major: KV[h][pos][32] =
// [k(16) | v(16)]. One 128-B line = 4 consecutive positions of one head ->
// the attention kernel's row-gathers touch ~3x fewer cache lines (x-runs of
// 10 contiguous positions), and K+V share lines (V staging warms K's lines).
// ---------------------------------------------------------------------------
__global__ __launch_bounds__(256, 3) void gemm_qkv_kernel(
    const float* __restrict__ x,
    const float* __restrict__ wq,
    const float* __restrict__ qkv_b,
    unsigned short* __restrict__ Qhl,   // [5760][256] bf16 q hi|lo per head
    unsigned short* __restrict__ KV)    // [8][5760][32] bf16 k|v head-major
{
    __shared__ __align__(16) unsigned short Bs[64][264];  // [hi128|lo128|pad8]

    const int tid = threadIdx.x;
    const int bn  = blockIdx.x * 64;
    const int bm  = blockIdx.y * 64;

    for (int i = tid; i < 2048; i += 256) {
        const int r = i >> 5, c4 = (i & 31) * 4;
        const float4 v = *(const float4*)(wq + (size_t)(bn + r) * 128 + c4);
        ushort4 hi, lo;
        hi.x = f2bf(v.x); hi.y = f2bf(v.y); hi.z = f2bf(v.z); hi.w = f2bf(v.w);
        lo.x = f2bf(v.x - bf2f(hi.x));
        lo.y = f2bf(v.y - bf2f(hi.y));
        lo.z = f2bf(v.z - bf2f(hi.z));
        lo.w = f2bf(v.w - bf2f(hi.w));
        *(ushort4*)(&Bs[r][c4])       = hi;
        *(ushort4*)(&Bs[r][128 + c4]) = lo;
    }
    __syncthreads();

    const int w    = tid >> 6;
    const int lane = tid & 63;
    const int ln   = lane & 15;
    const int quad = lane >> 4;
    const int row  = bm + w * 16 + ln;
    const float* ar = x + (size_t)row * 128 + quad * 8;

    f32x4 acc[4] = {};
    #pragma unroll
    for (int kcg = 0; kcg < 4; ++kcg) {
        const float4 xa = *(const float4*)(ar + kcg * 32);
        const float4 xb = *(const float4*)(ar + kcg * 32 + 4);
        bf16x8 ahi, alo;
        {
            const float vv[8] = {xa.x, xa.y, xa.z, xa.w, xb.x, xb.y, xb.z, xb.w};
            #pragma unroll
            for (int j = 0; j < 8; ++j) {
                const unsigned short hh = f2bf(vv[j]);
                ahi[j] = (short)hh;
                alo[j] = (short)f2bf(vv[j] - bf2f(hh));
            }
        }
        #pragma unroll
        for (int nt = 0; nt < 4; ++nt) {
            const bf16x8 bhi = *(const bf16x8*)(&Bs[nt * 16 + ln][kcg * 32 + quad * 8]);
            const bf16x8 blo = *(const bf16x8*)(&Bs[nt * 16 + ln][128 + kcg * 32 + quad * 8]);
            acc[nt] = __builtin_amdgcn_mfma_f32_16x16x32_bf16(ahi, bhi, acc[nt], 0, 0, 0);
            acc[nt] = __builtin_amdgcn_mfma_f32_16x16x32_bf16(alo, bhi, acc[nt], 0, 0, 0);
            acc[nt] = __builtin_amdgcn_mfma_f32_16x16x32_bf16(ahi, blo, acc[nt], 0, 0, 0);
        }
    }

    #pragma unroll
    for (int nt = 0; nt < 4; ++nt) {
        const int col = bn + nt * 16 + ln;
        const float bv = qkv_b[col];
        #pragma unroll
        for (int r = 0; r < 4; ++r) {
            const int orow = bm + w * 16 + quad * 4 + r;
            const float val = acc[nt][r] + bv;
            if (col < 128) {               // q -> hi/lo pair
                const int h = col >> 4, ci = col & 15;
                const unsigned short hi = f2bf(val);
                Qhl[(size_t)orow * 256 + h * 32 + ci]      = hi;
                Qhl[(size_t)orow * 256 + h * 32 + 16 + ci] = f2bf(val - bf2f(hi));
            } else if (col < 256) {        // k -> KV[h][row][ci]
                const int h = (col - 128) >> 4, ci = (col - 128) & 15;
                KV[((size_t)h * NPOS + orow) * 32 + ci] = f2bf(val);
            } else {                       // v -> KV[h][row][16+ci]
                const int h = (col - 256) >> 4, ci = (col - 256) & 15;
                KV[((size_t)h * NPOS + orow) * 32 + 16 + ci] = f2bf(val);
            }
        }
    }
}

// ---------------------------------------------------------------------------
// Proj GEMM (R11 verbatim): out = ((O0+O1) * 1/(l0+l1)) @ proj_w^T + b.
// ---------------------------------------------------------------------------
__global__ __launch_bounds__(128, 2) void gemm_proj_kernel(
    const float* __restrict__ Opart,   // [2][5760][128] fp32 unnormalized
    const float* __restrict__ Lpart,   // [2][5760][8]   fp32 row-sums
    const float* __restrict__ wp,
    const float* __restrict__ proj_b,
    float* __restrict__ out)
{
    __shared__ __align__(16) unsigned short Bs[64][264];

    const int tid = threadIdx.x;
    const int bn  = blockIdx.x * 64;
    const int bm  = blockIdx.y * 32;

    for (int i = tid; i < 2048; i += 128) {
        const int r = i >> 5, c4 = (i & 31) * 4;
        const float4 v = *(const float4*)(wp + (size_t)(bn + r) * 128 + c4);
        ushort4 hi, lo;
        hi.x = f2bf(v.x); hi.y = f2bf(v.y); hi.z = f2bf(v.z); hi.w = f2bf(v.w);
        lo.x = f2bf(v.x - bf2f(hi.x));
        lo.y = f2bf(v.y - bf2f(hi.y));
        lo.z = f2bf(v.z - bf2f(hi.z));
        lo.w = f2bf(v.w - bf2f(hi.w));
        *(ushort4*)(&Bs[r][c4])       = hi;
        *(ushort4*)(&Bs[r][128 + c4]) = lo;
    }
    __syncthreads();

    const int w    = tid >> 6;
    const int lane = tid & 63;
    const int ln   = lane & 15;
    const int quad = lane >> 4;
    const int row  = bm + w * 16 + ln;

    float linv[8];
    {
        const float4 l0a = *(const float4*)(Lpart + (size_t)row * 8);
        const float4 l0b = *(const float4*)(Lpart + (size_t)row * 8 + 4);
        const float4 l1a = *(const float4*)(Lpart + (size_t)(NPOS + row) * 8);
        const float4 l1b = *(const float4*)(Lpart + (size_t)(NPOS + row) * 8 + 4);
        linv[0] = 1.0f / (l0a.x + l1a.x); linv[1] = 1.0f / (l0a.y + l1a.y);
        linv[2] = 1.0f / (l0a.z + l1a.z); linv[3] = 1.0f / (l0a.w + l1a.w);
        linv[4] = 1.0f / (l0b.x + l1b.x); linv[5] = 1.0f / (l0b.y + l1b.y);
        linv[6] = 1.0f / (l0b.z + l1b.z); linv[7] = 1.0f / (l0b.w + l1b.w);
    }
    const float* o0 = Opart + (size_t)row * 128 + quad * 8;
    const float* o1 = o0 + (size_t)NPOS * 128;

    f32x4 acc[4] = {};
    #pragma unroll
    for (int kcg = 0; kcg < 4; ++kcg) {
        const float4 a0 = *(const float4*)(o0 + kcg * 32);
        const float4 a0b = *(const float4*)(o0 + kcg * 32 + 4);
        const float4 a1 = *(const float4*)(o1 + kcg * 32);
        const float4 a1b = *(const float4*)(o1 + kcg * 32 + 4);
        const float inv = linv[kcg * 2 + (quad >> 1)];
        const float vv[8] = {
            (a0.x + a1.x) * inv, (a0.y + a1.y) * inv,
            (a0.z + a1.z) * inv, (a0.w + a1.w) * inv,
            (a0b.x + a1b.x) * inv, (a0b.y + a1b.y) * inv,
            (a0b.z + a1b.z) * inv, (a0b.w + a1b.w) * inv };
        bf16x8 ahi, alo;
        #pragma unroll
        for (int j = 0; j < 8; ++j) {
            const unsigned short hh = f2bf(vv[j]);
            ahi[j] = (short)hh;
            alo[j] = (short)f2bf(vv[j] - bf2f(hh));
        }
        #pragma unroll
        for (int nt = 0; nt < 4; ++nt) {
            const bf16x8 bhi = *(const bf16x8*)(&Bs[nt * 16 + ln][kcg * 32 + quad * 8]);
            const bf16x8 blo = *(const bf16x8*)(&Bs[nt * 16 + ln][128 + kcg * 32 + quad * 8]);
            acc[nt] = __builtin_amdgcn_mfma_f32_16x16x32_bf16(ahi, bhi, acc[nt], 0, 0, 0);
            acc[nt] = __builtin_amdgcn_mfma_f32_16x16x32_bf16(alo, bhi, acc[nt], 0, 0, 0);
            acc[nt] = __builtin_amdgcn_mfma_f32_16x16x32_bf16(ahi, blo, acc[nt], 0, 0, 0);
        }
    }

    #pragma unroll
    for (int nt = 0; nt < 4; ++nt) {
        const int col = bn + nt * 16 + ln;
        const float bv = proj_b[col];
        #pragma unroll
        for (int r = 0; r < 4; ++r) {
            const int orow = bm + w * 16 + quad * 4 + r;
            out[(size_t)orow * 128 + col] = acc[nt][r] + bv;
        }
    }
}

// ---------------------------------------------------------------------------
// Attention (R11 structure verbatim; only KV-layout indexing + Vt pad 258).
// Grid (144, 8): tile = bx>>1, half = bx&1. 256 thr = 4 waves, each wave
// 2 chunks of 32 u. Outputs unnormalized fp32 O partials + l row-sums.
// K fragment loads and V staging now read the co-located KV[h][pos][32]
// rows — ~3x fewer distinct cache lines per gather, K/V share lines.
// ---------------------------------------------------------------------------
__global__ __launch_bounds__(256, 4) void attn_kernel(
    const unsigned short* __restrict__ Qhl,   // [5760][256] bf16 per-head hi|lo
    const unsigned short* __restrict__ KV,    // [8][5760][32] bf16 k|v
    float* __restrict__ Opart,                // [2][5760][128] fp32
    float* __restrict__ Lpart)                // [2][5760][8]   fp32
{
    // LDS: Vt[16][258]@0 (8256), Qb[80][40]@8448 (6400), Pw@14848 (10240),
    //      red_l@25088 (1280); redO overlay@0 (20480). Total 26368.
    __shared__ __align__(16) char smem[26368];
    unsigned short (*Vt)[258] = (unsigned short(*)[258])smem;
    unsigned short (*Qb)[40]  = (unsigned short(*)[40])(smem + 8448);
    unsigned short* PwBase    = (unsigned short*)(smem + 14848);
    float* red_l              = (float*)(smem + 25088);
    float* redO               = (float*)smem;

    const int bx   = blockIdx.x;
    const int tile = bx >> 1;
    const int half = bx & 1;
    const int h    = blockIdx.y;
    const int ty0  = (tile / 12) * 4;
    const int tx0  = (tile % 12) * 4;
    const int tid  = threadIdx.x;

    const unsigned short* KVh = KV + (size_t)h * NPOS * 32;

    // ---- stage V^T for this half's 256 u (reads warm K's lines too) ----
    for (int i = tid; i < 512; i += 256) {
        const int ul = i >> 1, hf8 = i & 1;
        const int u  = half * 256 + ul;
        if (u < 500) {
            const int dp = u / 100, rr = u % 100;
            const int uy = rr / 10, ux = rr % 10;
            int y = ty0 - 3 + uy; if (y < 0) y += HH;  if (y >= HH) y -= HH;
            int x = tx0 - 3 + ux; if (x < 0) x += WW_; if (x >= WW_) x -= WW_;
            const int g = (dp * HH + y) * WW_ + x;
            const bf16x8 v = *(const bf16x8*)(KVh + (size_t)g * 32 + 16 + hf8 * 8);
            #pragma unroll
            for (int c = 0; c < 8; ++c) Vt[hf8 * 8 + c][ul] = (unsigned short)v[c];
        } else {
            #pragma unroll
            for (int c = 0; c < 8; ++c) Vt[hf8 * 8 + c][ul] = 0;
        }
    }
    // ---- stage Q tile (straight bf16 copy) ----
    for (int i = tid; i < 320; i += 256) {
        const int p = i >> 2, seg = i & 3;
        const int d = p >> 4, s = p & 15;
        const int sy = s >> 2, sx = s & 3;
        const int g = (d * HH + ty0 + sy) * WW_ + tx0 + sx;
        *(bf16x8*)(&Qb[p][seg * 8]) = *(const bf16x8*)(Qhl + (size_t)g * 256 + h * 32 + seg * 8);
    }
    __syncthreads();

    const int w    = tid >> 6;
    const int lane = tid & 63;
    const int ln   = lane & 15;
    const int quad = lane >> 4;
    const int sy   = ln >> 2, sx = ln & 3;

    unsigned short* Pw = PwBase + w * 1280;  // [2][16][40]

    bf16x8 qf[5];
    #pragma unroll
    for (int mt = 0; mt < 5; ++mt)
        qf[mt] = *(const bf16x8*)(&Qb[mt * 16 + ln][quad * 8]);

    f32x4 Ow[5] = {};
    float lsum[5] = {};

    #pragma unroll
    for (int chunk = 0; chunk < 2; ++chunk) {
        const int u0g = (half * 8 + w * 2 + chunk) * 32;   // global u base
        const int u0l = (w * 2 + chunk) * 32;              // LDS-local u base

        int rowa, rowb;
        {
            const int ua = u0g + ln      < 500 ? u0g + ln      : 499;
            const int ub = u0g + 16 + ln < 500 ? u0g + 16 + ln : 499;
            int dp = ua / 100, rr = ua - dp * 100, yy = rr / 10, xx = rr - yy * 10;
            int y = ty0 - 3 + yy; if (y < 0) y += HH;  if (y >= HH) y -= HH;
            int x = tx0 - 3 + xx; if (x < 0) x += WW_; if (x >= WW_) x -= WW_;
            rowa = (dp * HH + y) * WW_ + x;
            dp = ub / 100; rr = ub - dp * 100; yy = rr / 10; xx = rr - yy * 10;
            y = ty0 - 3 + yy; if (y < 0) y += HH;  if (y >= HH) y -= HH;
            x = tx0 - 3 + xx; if (x < 0) x += WW_; if (x >= WW_) x -= WW_;
            rowb = (dp * HH + y) * WW_ + x;
        }
        const bf16x8 ka = *(const bf16x8*)(KVh + (size_t)rowa * 32 + (quad & 1) * 8);
        const bf16x8 kb = *(const bf16x8*)(KVh + (size_t)rowb * 32 + (quad & 1) * 8);

        bool msk[2][4];
        #pragma unroll
        for (int b = 0; b < 2; ++b)
            #pragma unroll
            for (int r = 0; r < 4; ++r) {
                const int u = u0g + 16 * b + 4 * quad + r;
                const int rr = u % 100;
                const int uy = rr / 10, ux = rr - uy * 10;
                msk[b][r] = (u < 500) && ((unsigned)(uy - sy) <= 6u)
                                      && ((unsigned)(ux - sx) <= 6u);
            }

        const bf16x8 vf = *(const bf16x8*)(&Vt[ln][u0l + quad * 8]);

        #pragma unroll
        for (int mt = 0; mt < 5; ++mt) {
            f32x4 s0 = __builtin_amdgcn_mfma_f32_16x16x32_bf16(
                ka, qf[mt], (f32x4){0.f, 0.f, 0.f, 0.f}, 0, 0, 0);
            f32x4 s1 = __builtin_amdgcn_mfma_f32_16x16x32_bf16(
                kb, qf[mt], (f32x4){0.f, 0.f, 0.f, 0.f}, 0, 0, 0);

            unsigned short* pw = Pw + (mt & 1) * 640 + ln * 40;
            #pragma unroll
            for (int b = 0; b < 2; ++b) {
                const f32x4 s = b ? s1 : s0;
                unsigned short e[4];
                #pragma unroll
                for (int r = 0; r < 4; ++r) {
                    const float ev = msk[b][r] ? __expf(fmaf(s[r], SCALE, -8.0f)) : 0.f;
                    e[r] = f2bf(ev);
                    lsum[mt] += bf2f(e[r]);
                }
                *(unsigned*)(pw + 16 * b + 4 * quad)     = (unsigned)e[0] | ((unsigned)e[1] << 16);
                *(unsigned*)(pw + 16 * b + 4 * quad + 2) = (unsigned)e[2] | ((unsigned)e[3] << 16);
            }
            const bf16x8 pf = *(const bf16x8*)(Pw + (mt & 1) * 640 + ln * 40 + quad * 8);
            Ow[mt] = __builtin_amdgcn_mfma_f32_16x16x32_bf16(vf, pf, Ow[mt], 0, 0, 0);
        }
    }

    // l: lanes (ln, quad) hold disjoint u-partials -> reduce across quads
    #pragma unroll
    for (int mt = 0; mt < 5; ++mt) {
        lsum[mt] += __shfl_xor(lsum[mt], 16);
        lsum[mt] += __shfl_xor(lsum[mt], 32);
    }

    __syncthreads();   // all Vt/Qb/Pw reads done; safe to overlay redO

    if (quad == 0) {
        #pragma unroll
        for (int mt = 0; mt < 5; ++mt)
            red_l[w * 80 + mt * 16 + ln] = lsum[mt];
    }
    #pragma unroll
    for (int mt = 0; mt < 5; ++mt)
        #pragma unroll
        for (int r = 0; r < 4; ++r)
            redO[(size_t)((w * 5 + mt) * 16 + quad * 4 + r) * 16 + ln] = Ow[mt][r];
    __syncthreads();

    // final: sum 4 wave-partials, write fp32 partials (no division)
    for (int i = tid; i < 1280; i += 256) {
        const int m = i >> 4, c = i & 15;
        const int mt = m >> 4, mloc = m & 15;
        float o = 0.f, l = 0.f;
        #pragma unroll
        for (int w4 = 0; w4 < 4; ++w4) {
            o += redO[(size_t)((w4 * 5 + mt) * 16 + c) * 16 + mloc];
            l += red_l[w4 * 80 + m];
        }
        const int qsy = (mloc >> 2), qsx = mloc & 3;
        const size_t g = (size_t)((mt * HH + ty0 + qsy) * WW_ + (tx0 + qsx));
        Opart[((size_t)half * NPOS + g) * 128 + h * HDIM + c] = o;
        if (c == 0) Lpart[((size_t)half * NPOS + g) * 8 + h] = l;
    }
}

// ---------------------------------------------------------------------------
extern "C" void kernel_launch(void* const* d_in, const int* in_sizes, int n_in,
                              void* d_out, int out_size, void* d_ws, size_t ws_size,
                              hipStream_t stream)
{
    const float* x      = (const float*)d_in[0];
    const float* qkv_w  = (const float*)d_in[1];
    const float* qkv_b  = (const float*)d_in[2];
    const float* proj_w = (const float*)d_in[3];
    const float* proj_b = (const float*)d_in[4];
    float* out = (float*)d_out;

    char* ws = (char*)d_ws;
    unsigned short* Qhl   = (unsigned short*)ws;  ws += (size_t)NPOS * 256 * 2;
    unsigned short* KV    = (unsigned short*)ws;  ws += (size_t)NHEADS * NPOS * 32 * 2;
    float*          Opart = (float*)ws;           ws += (size_t)2 * NPOS * 128 * 4;
    float*          Lpart = (float*)ws;           ws += (size_t)2 * NPOS * 8 * 4;

    // 1. QKV GEMM -> Qhl, KV (co-located head-major)
    {
        dim3 grid(384 / 64, NPOS / 64);
        gemm_qkv_kernel<<<grid, 256, 0, stream>>>(x, qkv_w, qkv_b, Qhl, KV);
    }
    // 2. attention (u-split) -> Opart/Lpart
    {
        dim3 grid(144, NHEADS);
        attn_kernel<<<grid, 256, 0, stream>>>(Qhl, KV, Opart, Lpart);
    }
    // 3. proj GEMM (combine halves + normalize + GEMM) -> out
    {
        dim3 grid(DIMC / 64, NPOS / 32);
        gemm_proj_kernel<<<grid, 128, 0, stream>>>(Opart, Lpart, proj_w, proj_b, out);
    }
}

// Round 16
// 98.579 us; speedup vs baseline: 1.0598x; 1.0127x over previous
//
#include <hip/hip_runtime.h>
#include <hip/hip_bf16.h>
#include <cstddef>

// Problem constants
#define DIMC   128
#define NHEADS 8
#define HDIM   16
#define DD     5
#define HH     24
#define WW_    48
#define NPOS   (DD * HH * WW_)     // 5760
#define SCALE  0.25f

typedef short  bf16x8 __attribute__((ext_vector_type(8)));
typedef float  f32x4  __attribute__((ext_vector_type(4)));

__device__ __forceinline__ unsigned short f2bf(float f) {
    unsigned u = __float_as_uint(f);
    u = (u + 0x7FFFu + ((u >> 16) & 1u)) >> 16;   // RNE
    return (unsigned short)u;
}
__device__ __forceinline__ float bf2f(unsigned short s) {
    return __uint_as_float(((unsigned)s) << 16);
}

// ---------------------------------------------------------------------------
// QKV GEMM with fused fp32->bf16 hi/lo conversion.
// C[M][384] = x[M][128] @ qkv_w[384][128]^T + b as 3-term bf16 split:
// hi*hi + lo*hi + hi*lo (missing lo*lo ~2^-18).
// ---------------------------------------------------------------------------
__global__ __launch_bounds__(256, 3) void gemm_qkv_kernel(
    const float* __restrict__ x,
    const float* __restrict__ wq,
    const float* __restrict__ qkv_b,
    unsigned short* __restrict__ Qhl,
    unsigned short* __restrict__ Kbf,
    unsigned short* __restrict__ Vbf)
{
    __shared__ __align__(16) unsigned short Bs[64][264];  // [hi128|lo128|pad8]

    const int tid = threadIdx.x;
    const int bn  = blockIdx.x * 64;
    const int bm  = blockIdx.y * 64;

    for (int i = tid; i < 2048; i += 256) {
        const int r = i >> 5, c4 = (i & 31) * 4;
        const float4 v = *(const float4*)(wq + (size_t)(bn + r) * 128 + c4);
        ushort4 hi, lo;
        hi.x = f2bf(v.x); hi.y = f2bf(v.y); hi.z = f2bf(v.z); hi.w = f2bf(v.w);
        lo.x = f2bf(v.x - bf2f(hi.x));
        lo.y = f2bf(v.y - bf2f(hi.y));
        lo.z = f2bf(v.z - bf2f(hi.z));
        lo.w = f2bf(v.w - bf2f(hi.w));
        *(ushort4*)(&Bs[r][c4])       = hi;
        *(ushort4*)(&Bs[r][128 + c4]) = lo;
    }
    __syncthreads();

    const int w    = tid >> 6;
    const int lane = tid & 63;
    const int ln   = lane & 15;
    const int quad = lane >> 4;
    const int row  = bm + w * 16 + ln;
    const float* ar = x + (size_t)row * 128 + quad * 8;

    f32x4 acc[4] = {};
    #pragma unroll
    for (int kcg = 0; kcg < 4; ++kcg) {
        const float4 xa = *(const float4*)(ar + kcg * 32);
        const float4 xb = *(const float4*)(ar + kcg * 32 + 4);
        bf16x8 ahi, alo;
        {
            const float vv[8] = {xa.x, xa.y, xa.z, xa.w, xb.x, xb.y, xb.z, xb.w};
            #pragma unroll
            for (int j = 0; j < 8; ++j) {
                const unsigned short hh = f2bf(vv[j]);
                ahi[j] = (short)hh;
                alo[j] = (short)f2bf(vv[j] - bf2f(hh));
            }
        }
        #pragma unroll
        for (int nt = 0; nt < 4; ++nt) {
            const bf16x8 bhi = *(const bf16x8*)(&Bs[nt * 16 + ln][kcg * 32 + quad * 8]);
            const bf16x8 blo = *(const bf16x8*)(&Bs[nt * 16 + ln][128 + kcg * 32 + quad * 8]);
            acc[nt] = __builtin_amdgcn_mfma_f32_16x16x32_bf16(ahi, bhi, acc[nt], 0, 0, 0);
            acc[nt] = __builtin_amdgcn_mfma_f32_16x16x32_bf16(alo, bhi, acc[nt], 0, 0, 0);
            acc[nt] = __builtin_amdgcn_mfma_f32_16x16x32_bf16(ahi, blo, acc[nt], 0, 0, 0);
        }
    }

    #pragma unroll
    for (int nt = 0; nt < 4; ++nt) {
        const int col = bn + nt * 16 + ln;
        const float bv = qkv_b[col];
        #pragma unroll
        for (int r = 0; r < 4; ++r) {
            const int orow = bm + w * 16 + quad * 4 + r;
            const float val = acc[nt][r] + bv;
            if (col < 128) {               // q -> hi/lo pair
                const int h = col >> 4, ci = col & 15;
                const unsigned short hi = f2bf(val);
                Qhl[(size_t)orow * 256 + h * 32 + ci]      = hi;
                Qhl[(size_t)orow * 256 + h * 32 + 16 + ci] = f2bf(val - bf2f(hi));
            } else if (col < 256) {        // k -> bf16
                Kbf[(size_t)orow * 128 + (col - 128)] = f2bf(val);
            } else {                       // v -> bf16
                Vbf[(size_t)orow * 128 + (col - 256)] = f2bf(val);
            }
        }
    }
}

// ---------------------------------------------------------------------------
// Proj GEMM: out = ((O0+O1) * 1/(l0+l1)) @ proj_w^T + b.
// A built in-registers from attn's fp32 partials (combine + normalize +
// hi/lo split); B converted fp32->hi|lo into LDS. Per kcg the 8 fragment
// channels lie in ONE head: h = kcg*2 + (quad>>1) -> one scalar inv each.
// Grid (2, 180) = 360 blocks of 128 thr.
// ---------------------------------------------------------------------------
__global__ __launch_bounds__(128, 2) void gemm_proj_kernel(
    const float* __restrict__ Opart,   // [2][5760][128] fp32 unnormalized
    const float* __restrict__ Lpart,   // [2][5760][8]   fp32 row-sums
    const float* __restrict__ wp,
    const float* __restrict__ proj_b,
    float* __restrict__ out)
{
    __shared__ __align__(16) unsigned short Bs[64][264];

    const int tid = threadIdx.x;
    const int bn  = blockIdx.x * 64;
    const int bm  = blockIdx.y * 32;

    for (int i = tid; i < 2048; i += 128) {
        const int r = i >> 5, c4 = (i & 31) * 4;
        const float4 v = *(const float4*)(wp + (size_t)(bn + r) * 128 + c4);
        ushort4 hi, lo;
        hi.x = f2bf(v.x); hi.y = f2bf(v.y); hi.z = f2bf(v.z); hi.w = f2bf(v.w);
        lo.x = f2bf(v.x - bf2f(hi.x));
        lo.y = f2bf(v.y - bf2f(hi.y));
        lo.z = f2bf(v.z - bf2f(hi.z));
        lo.w = f2bf(v.w - bf2f(hi.w));
        *(ushort4*)(&Bs[r][c4])       = hi;
        *(ushort4*)(&Bs[r][128 + c4]) = lo;
    }
    __syncthreads();

    const int w    = tid >> 6;
    const int lane = tid & 63;
    const int ln   = lane & 15;
    const int quad = lane >> 4;
    const int row  = bm + w * 16 + ln;

    float linv[8];
    {
        const float4 l0a = *(const float4*)(Lpart + (size_t)row * 8);
        const float4 l0b = *(const float4*)(Lpart + (size_t)row * 8 + 4);
        const float4 l1a = *(const float4*)(Lpart + (size_t)(NPOS + row) * 8);
        const float4 l1b = *(const float4*)(Lpart + (size_t)(NPOS + row) * 8 + 4);
        linv[0] = 1.0f / (l0a.x + l1a.x); linv[1] = 1.0f / (l0a.y + l1a.y);
        linv[2] = 1.0f / (l0a.z + l1a.z); linv[3] = 1.0f / (l0a.w + l1a.w);
        linv[4] = 1.0f / (l0b.x + l1b.x); linv[5] = 1.0f / (l0b.y + l1b.y);
        linv[6] = 1.0f / (l0b.z + l1b.z); linv[7] = 1.0f / (l0b.w + l1b.w);
    }
    const float* o0 = Opart + (size_t)row * 128 + quad * 8;
    const float* o1 = o0 + (size_t)NPOS * 128;

    f32x4 acc[4] = {};
    #pragma unroll
    for (int kcg = 0; kcg < 4; ++kcg) {
        const float4 a0 = *(const float4*)(o0 + kcg * 32);
        const float4 a0b = *(const float4*)(o0 + kcg * 32 + 4);
        const float4 a1 = *(const float4*)(o1 + kcg * 32);
        const float4 a1b = *(const float4*)(o1 + kcg * 32 + 4);
        const float inv = linv[kcg * 2 + (quad >> 1)];
        const float vv[8] = {
            (a0.x + a1.x) * inv, (a0.y + a1.y) * inv,
            (a0.z + a1.z) * inv, (a0.w + a1.w) * inv,
            (a0b.x + a1b.x) * inv, (a0b.y + a1b.y) * inv,
            (a0b.z + a1b.z) * inv, (a0b.w + a1b.w) * inv };
        bf16x8 ahi, alo;
        #pragma unroll
        for (int j = 0; j < 8; ++j) {
            const unsigned short hh = f2bf(vv[j]);
            ahi[j] = (short)hh;
            alo[j] = (short)f2bf(vv[j] - bf2f(hh));
        }
        #pragma unroll
        for (int nt = 0; nt < 4; ++nt) {
            const bf16x8 bhi = *(const bf16x8*)(&Bs[nt * 16 + ln][kcg * 32 + quad * 8]);
            const bf16x8 blo = *(const bf16x8*)(&Bs[nt * 16 + ln][128 + kcg * 32 + quad * 8]);
            acc[nt] = __builtin_amdgcn_mfma_f32_16x16x32_bf16(ahi, bhi, acc[nt], 0, 0, 0);
            acc[nt] = __builtin_amdgcn_mfma_f32_16x16x32_bf16(alo, bhi, acc[nt], 0, 0, 0);
            acc[nt] = __builtin_amdgcn_mfma_f32_16x16x32_bf16(ahi, blo, acc[nt], 0, 0, 0);
        }
    }

    #pragma unroll
    for (int nt = 0; nt < 4; ++nt) {
        const int col = bn + nt * 16 + ln;
        const float bv = proj_b[col];
        #pragma unroll
        for (int r = 0; r < 4; ++r) {
            const int orow = bm + w * 16 + quad * 4 + r;
            out[(size_t)orow * 128 + col] = acc[nt][r] + bv;
        }
    }
}

// ---------------------------------------------------------------------------
// Fused neighborhood attention: u-range split across 2 blocks.
// Grid (144, 8): tile = bx>>1, half = bx&1. Block covers u in
// [half*256, half*256+256); 4 waves x 2 chunks of 32 each. Output:
// UNNORMALIZED fp32 O partials + l row-sums; proj combines and normalizes.
// 1152 blocks = 4.5/CU; LDS 26.4 KB.
// ---------------------------------------------------------------------------
__global__ __launch_bounds__(256, 4) void attn_kernel(
    const unsigned short* __restrict__ Qhl,   // [5760][256] bf16 per-head hi|lo
    const unsigned short* __restrict__ Kbf,   // [5760][128] bf16
    const unsigned short* __restrict__ Vbf,   // [5760][128] bf16
    float* __restrict__ Opart,                // [2][5760][128] fp32
    float* __restrict__ Lpart)                // [2][5760][8]   fp32
{
    // LDS layout:
    //   Vt   : ushort[16][264]  @     0   (8448 B)  V^T for this u-half
    //   Qb   : ushort[80][40]   @  8448   (6400 B)
    //   Pw   : ushort[4][2][16][40] @ 14848 (10240 B)
    //   red_l: float[4][80]     @ 25088   (1280 B)
    //   redO : float[4*5*16][16] @ 0      (20480 B) overlay post-barrier
    __shared__ __align__(16) char smem[26368];
    unsigned short (*Vt)[264] = (unsigned short(*)[264])smem;
    unsigned short (*Qb)[40]  = (unsigned short(*)[40])(smem + 8448);
    unsigned short* PwBase    = (unsigned short*)(smem + 14848);
    float* red_l              = (float*)(smem + 25088);
    float* redO               = (float*)smem;

    const int bx   = blockIdx.x;
    const int tile = bx >> 1;
    const int half = bx & 1;
    const int h    = blockIdx.y;
    const int ty0  = (tile / 12) * 4;
    const int tx0  = (tile % 12) * 4;
    const int tid  = threadIdx.x;

    // ---- stage V^T for this half's 256 u ----
    for (int i = tid; i < 512; i += 256) {
        const int ul = i >> 1, hf8 = i & 1;
        const int u  = half * 256 + ul;
        if (u < 500) {
            const int dp = u / 100;
            const int rr = u - dp * 100;
            const int yy = rr / 10;
            const int xx = rr - yy * 10;
            int y = ty0 - 3 + yy; if (y < 0) y += HH;  if (y >= HH) y -= HH;
            int x = tx0 - 3 + xx; if (x < 0) x += WW_; if (x >= WW_) x -= WW_;
            const int g = (dp * HH + y) * WW_ + x;
            const bf16x8 v = *(const bf16x8*)(Vbf + (size_t)g * 128 + h * 16 + hf8 * 8);
            #pragma unroll
            for (int c = 0; c < 8; ++c) Vt[hf8 * 8 + c][ul] = (unsigned short)v[c];
        } else {
            #pragma unroll
            for (int c = 0; c < 8; ++c) Vt[hf8 * 8 + c][ul] = 0;
        }
    }
    // ---- stage Q tile (straight bf16 copy) ----
    for (int i = tid; i < 320; i += 256) {
        const int p = i >> 2, seg = i & 3;
        const int d = p >> 4, s = p & 15;
        const int sy = s >> 2, sx = s & 3;
        const int g = (d * HH + ty0 + sy) * WW_ + tx0 + sx;
        *(bf16x8*)(&Qb[p][seg * 8]) = *(const bf16x8*)(Qhl + (size_t)g * 256 + h * 32 + seg * 8);
    }
    __syncthreads();

    const int w    = tid >> 6;
    const int lane = tid & 63;
    const int ln   = lane & 15;
    const int quad = lane >> 4;
    const int sy   = ln >> 2, sx = ln & 3;

    unsigned short* Pw = PwBase + w * 1280;  // [2][16][40]

    bf16x8 qf[5];
    #pragma unroll
    for (int mt = 0; mt < 5; ++mt)
        qf[mt] = *(const bf16x8*)(&Qb[mt * 16 + ln][quad * 8]);

    f32x4 Ow[5] = {};
    float lsum[5] = {};

    #pragma unroll
    for (int chunk = 0; chunk < 2; ++chunk) {
        const int u0g = (half * 8 + w * 2 + chunk) * 32;   // global u base
        const int u0l = (w * 2 + chunk) * 32;              // LDS-local u base

        int rowa, rowb;
        {
            const int ua = u0g + ln      < 500 ? u0g + ln      : 499;
            const int ub = u0g + 16 + ln < 500 ? u0g + 16 + ln : 499;
            int dp = ua / 100, rr = ua - dp * 100, yy = rr / 10, xx = rr - yy * 10;
            int y = ty0 - 3 + yy; if (y < 0) y += HH;  if (y >= HH) y -= HH;
            int x = tx0 - 3 + xx; if (x < 0) x += WW_; if (x >= WW_) x -= WW_;
            rowa = (dp * HH + y) * WW_ + x;
            dp = ub / 100; rr = ub - dp * 100; yy = rr / 10; xx = rr - yy * 10;
            y = ty0 - 3 + yy; if (y < 0) y += HH;  if (y >= HH) y -= HH;
            x = tx0 - 3 + xx; if (x < 0) x += WW_; if (x >= WW_) x -= WW_;
            rowb = (dp * HH + y) * WW_ + x;
        }
        const bf16x8 ka = *(const bf16x8*)(Kbf + (size_t)rowa * 128 + h * 16 + (quad & 1) * 8);
        const bf16x8 kb = *(const bf16x8*)(Kbf + (size_t)rowb * 128 + h * 16 + (quad & 1) * 8);

        bool msk[2][4];
        #pragma unroll
        for (int b = 0; b < 2; ++b)
            #pragma unroll
            for (int r = 0; r < 4; ++r) {
                const int u = u0g + 16 * b + 4 * quad + r;
                const int rr = u % 100;
                const int uy = rr / 10, ux = rr - uy * 10;
                msk[b][r] = (u < 500) && ((unsigned)(uy - sy) <= 6u)
                                      && ((unsigned)(ux - sx) <= 6u);
            }

        const bf16x8 vf = *(const bf16x8*)(&Vt[ln][u0l + quad * 8]);

        #pragma unroll
        for (int mt = 0; mt < 5; ++mt) {
            f32x4 s0 = __builtin_amdgcn_mfma_f32_16x16x32_bf16(
                ka, qf[mt], (f32x4){0.f, 0.f, 0.f, 0.f}, 0, 0, 0);
            f32x4 s1 = __builtin_amdgcn_mfma_f32_16x16x32_bf16(
                kb, qf[mt], (f32x4){0.f, 0.f, 0.f, 0.f}, 0, 0, 0);

            unsigned short* pw = Pw + (mt & 1) * 640 + ln * 40;
            #pragma unroll
            for (int b = 0; b < 2; ++b) {
                const f32x4 s = b ? s1 : s0;
                unsigned short e[4];
                #pragma unroll
                for (int r = 0; r < 4; ++r) {
                    const float ev = msk[b][r] ? __expf(fmaf(s[r], SCALE, -8.0f)) : 0.f;
                    e[r] = f2bf(ev);
                    lsum[mt] += bf2f(e[r]);
                }
                *(unsigned*)(pw + 16 * b + 4 * quad)     = (unsigned)e[0] | ((unsigned)e[1] << 16);
                *(unsigned*)(pw + 16 * b + 4 * quad + 2) = (unsigned)e[2] | ((unsigned)e[3] << 16);
            }
            const bf16x8 pf = *(const bf16x8*)(Pw + (mt & 1) * 640 + ln * 40 + quad * 8);
            Ow[mt] = __builtin_amdgcn_mfma_f32_16x16x32_bf16(vf, pf, Ow[mt], 0, 0, 0);
        }
    }

    // l: lanes (ln, quad) hold disjoint u-partials -> reduce across quads
    #pragma unroll
    for (int mt = 0; mt < 5; ++mt) {
        lsum[mt] += __shfl_xor(lsum[mt], 16);
        lsum[mt] += __shfl_xor(lsum[mt], 32);
    }

    __syncthreads();   // all Vt/Qb/Pw reads done; safe to overlay redO

    if (quad == 0) {
        #pragma unroll
        for (int mt = 0; mt < 5; ++mt)
            red_l[w * 80 + mt * 16 + ln] = lsum[mt];
    }
    #pragma unroll
    for (int mt = 0; mt < 5; ++mt)
        #pragma unroll
        for (int r = 0; r < 4; ++r)
            redO[(size_t)((w * 5 + mt) * 16 + quad * 4 + r) * 16 + ln] = Ow[mt][r];
    __syncthreads();

    // final: sum 4 wave-partials, write fp32 partials (no division)
    for (int i = tid; i < 1280; i += 256) {
        const int m = i >> 4, c = i & 15;
        const int mt = m >> 4, mloc = m & 15;
        float o = 0.f, l = 0.f;
        #pragma unroll
        for (int w4 = 0; w4 < 4; ++w4) {
            o += redO[(size_t)((w4 * 5 + mt) * 16 + c) * 16 + mloc];
            l += red_l[w4 * 80 + m];
        }
        const int qsy = (mloc >> 2), qsx = mloc & 3;
        const size_t g = (size_t)((mt * HH + ty0 + qsy) * WW_ + (tx0 + qsx));
        Opart[((size_t)half * NPOS + g) * 128 + h * HDIM + c] = o;
        if (c == 0) Lpart[((size_t)half * NPOS + g) * 8 + h] = l;
    }
}

// ---------------------------------------------------------------------------
extern "C" void kernel_launch(void* const* d_in, const int* in_sizes, int n_in,
                              void* d_out, int out_size, void* d_ws, size_t ws_size,
                              hipStream_t stream)
{
    const float* x      = (const float*)d_in[0];
    const float* qkv_w  = (const float*)d_in[1];
    const float* qkv_b  = (const float*)d_in[2];
    const float* proj_w = (const float*)d_in[3];
    const float* proj_b = (const float*)d_in[4];
    float* out = (float*)d_out;

    char* ws = (char*)d_ws;
    unsigned short* Qhl   = (unsigned short*)ws;  ws += (size_t)NPOS * 256 * 2;
    unsigned short* Kbf   = (unsigned short*)ws;  ws += (size_t)NPOS * 128 * 2;
    unsigned short* Vbf   = (unsigned short*)ws;  ws += (size_t)NPOS * 128 * 2;
    float*          Opart = (float*)ws;           ws += (size_t)2 * NPOS * 128 * 4;
    float*          Lpart = (float*)ws;           ws += (size_t)2 * NPOS * 8 * 4;

    // 1. QKV GEMM (fused fp32->hi/lo conversion) -> Qhl, Kbf, Vbf
    {
        dim3 grid(384 / 64, NPOS / 64);
        gemm_qkv_kernel<<<grid, 256, 0, stream>>>(x, qkv_w, qkv_b, Qhl, Kbf, Vbf);
    }
    // 2. fused neighborhood attention (u-split, 1152 blocks) -> Opart/Lpart
    {
        dim3 grid(144, NHEADS);
        attn_kernel<<<grid, 256, 0, stream>>>(Qhl, Kbf, Vbf, Opart, Lpart);
    }
    // 3. proj GEMM (combine halves + normalize + GEMM) -> out
    {
        dim3 grid(DIMC / 64, NPOS / 32);
        gemm_proj_kernel<<<grid, 128, 0, stream>>>(Opart, Lpart, proj_w, proj_b, out);
    }
}